// Round 16
// baseline (154.781 us; speedup 1.0000x reference)
//
#include <hip/hip_runtime.h>

constexpr int NPIX  = 1 << 20;      // 1024*1024 pixels
constexpr int NCLS  = 21;
constexpr int NBINS = 240;          // linear bins over [0,8): width = 1/30
constexpr float RANGE = 8.0f;
constexpr float BIN_SCALE = NBINS / RANGE;   // 30
constexpr int NCHUNK = 32;
constexpr int CHUNK_PIX = NPIX / NCHUNK;     // 32768 (fits u16 bin counts)

typedef int   iv4 __attribute__((ext_vector_type(4)));
typedef float fv4 __attribute__((ext_vector_type(4)));

// ---------------------------------------------------------------------------
// 1) per-pixel argmax (single-phase label stream, ~6 TB/s).
//    int4 loads, uchar4 result (1 MB -> L2-resident for k_hist's re-reads).
//    Block 0 also zeroes global hist (40.3 KB), per-class tickets, out[0].
// ---------------------------------------------------------------------------
__global__ void k_argmax(const iv4* __restrict__ label4, uchar4* __restrict__ lbl,
                         unsigned long long* __restrict__ hist,
                         unsigned int* __restrict__ cnt,
                         float* __restrict__ out) {
    int i = blockIdx.x * blockDim.x + threadIdx.x;     // over NPIX/4
    if (blockIdx.x == 0) {
        for (int b = threadIdx.x; b < NCLS * NBINS; b += blockDim.x)
            hist[b] = 0ULL;
        if (threadIdx.x < NCLS) cnt[threadIdx.x] = 0u;
        if (threadIdx.x == 0) out[0] = 0.0f;
    }
    if (i >= NPIX / 4) return;
    iv4 best = label4[i];
    int bx = 0, by = 0, bz = 0, bw = 0;
    #pragma unroll
    for (int c = 1; c < NCLS; ++c) {
        iv4 v = label4[(size_t)c * (NPIX / 4) + i];
        if (v.x > best.x) { best.x = v.x; bx = c; }    // strict > keeps FIRST max
        if (v.y > best.y) { best.y = v.y; by = c; }
        if (v.z > best.z) { best.z = v.z; bz = c; }
        if (v.w > best.w) { best.w = v.w; bw = c; }
    }
    lbl[i] = make_uchar4((unsigned char)bx, (unsigned char)by,
                         (unsigned char)bz, (unsigned char)bw);
}

// ---------------------------------------------------------------------------
// 2) per-(chunk, class) histogram with 4-way replicated LDS sub-histograms
//    + LAST-BLOCK-PER-CLASS fused scan (ticket via cnt[c]): the 32nd block
//    of each class column runs that class's 240-bin shuffle-scan + Lovasz
//    dot + mean contribution — no third kernel launch.
// ---------------------------------------------------------------------------
__global__ void __launch_bounds__(512)
k_hist(const fv4* __restrict__ pred4, const uint2* __restrict__ lbl8,
       unsigned long long* __restrict__ hist, unsigned int* __restrict__ cnt,
       float* __restrict__ out) {
    __shared__ unsigned int sh[4][NBINS];              // 3.75 KB
    const int chunk = blockIdx.x;
    const int c     = blockIdx.y;
    const int t     = threadIdx.x;
    const int cp    = t & 3;

    for (int b = t; b < 4 * NBINS; b += 512) sh[b / NBINS][b % NBINS] = 0u;
    __syncthreads();

    const size_t pbase4 = ((size_t)c * NPIX + (size_t)chunk * CHUNK_PIX) / 4;
    const size_t lbase8 = ((size_t)chunk * CHUNK_PIX) / 8;
    constexpr int NPAIR = CHUNK_PIX / 8;               // 4096 quad-pairs

    #pragma unroll 2
    for (int k = t; k < NPAIR; k += 512) {
        fv4 p0 = pred4[pbase4 + 2 * k];
        fv4 p1 = pred4[pbase4 + 2 * k + 1];
        uint2 lw = lbl8[lbase8 + k];                   // 8 packed uchar labels
        unsigned int la = lw.x, lb = lw.y;

        float pe[8] = { p0.x, p0.y, p0.z, p0.w, p1.x, p1.y, p1.z, p1.w };
        unsigned int lc[8] = { la & 0xFFu, (la >> 8) & 0xFFu,
                               (la >> 16) & 0xFFu, la >> 24,
                               lb & 0xFFu, (lb >> 8) & 0xFFu,
                               (lb >> 16) & 0xFFu, lb >> 24 };
        #pragma unroll
        for (int j = 0; j < 8; ++j) {
            unsigned int fg = (lc[j] == (unsigned int)c) ? 1u : 0u;
            float e = fabsf((float)fg - pe[j]);
            int bin = (int)(e * BIN_SCALE);
            bin = bin < NBINS - 1 ? bin : NBINS - 1;
            atomicAdd(&sh[cp][bin], 1u | (fg << 16));
        }
    }
    __syncthreads();

    // flush: packed sum of the 4 copies, one u64 atomic per non-empty bin
    for (int b = t; b < NBINS; b += 512) {
        unsigned int v = sh[0][b] + sh[1][b] + sh[2][b] + sh[3][b];
        if (v) {
            unsigned long long add =
                (unsigned long long)(v & 0xFFFFu) |
                ((unsigned long long)(v >> 16) << 32);
            atomicAdd(&hist[(size_t)c * NBINS + b], add);
        }
    }

    // ---- ticket: last block of this class column does the scan
    __shared__ bool is_last;
    __threadfence();                                   // release: flush visible
    __syncthreads();
    if (t == 0) {
        unsigned int done = atomicAdd(&cnt[c], 1u);
        is_last = (done == NCHUNK - 1);
    }
    __syncthreads();
    if (!is_last) return;
    __threadfence();                                   // acquire

    // ---- per-class descending scan + Lovasz dot + mean (512 thr, 8 waves)
    const int lane = t & 63;
    const int wv   = t >> 6;

    const int bin = NBINS - 1 - t;                     // valid when t < NBINS
    unsigned int tn = 0, tf = 0;
    if (t < NBINS) {
        // atomic read (bypasses L1 -> no stale lines from argmax's zeroing)
        unsigned long long v = atomicAdd(&hist[(size_t)c * NBINS + bin], 0ULL);
        tn = (unsigned int)v;
        tf = (unsigned int)(v >> 32);
    }

    unsigned int in_ = tn, if_ = tf;
    #pragma unroll
    for (int off = 1; off < 64; off <<= 1) {
        unsigned int an = __shfl_up(in_, off, 64);
        unsigned int af = __shfl_up(if_, off, 64);
        if (lane >= off) { in_ += an; if_ += af; }
    }

    __shared__ unsigned int swn[8], swf[8];
    if (lane == 63) { swn[wv] = in_; swf[wv] = if_; }
    __syncthreads();

    if (wv == 0 && lane < 8) {                         // scan the 8 wave totals
        unsigned int a = swn[lane], b = swf[lane];
        #pragma unroll
        for (int off = 1; off < 8; off <<= 1) {
            unsigned int an = __shfl_up(a, off, 64);
            unsigned int af = __shfl_up(b, off, 64);
            if (lane >= off) { a += an; b += af; }
        }
        swn[lane] = a; swf[lane] = b;                  // inclusive wave prefixes
    }
    __syncthreads();

    const unsigned int G = swf[7];                     // total foreground count
    unsigned int i = in_ - tn + (wv ? swn[wv - 1] : 0u);   // exclusive prefix
    unsigned int F = if_ - tf + (wv ? swf[wv - 1] : 0u);

    double acc = 0.0;
    if (tn) {
        double jprev = (i > 0) ? (double)i / (double)(G + i - F) : 0.0;
        unsigned int i2 = i + tn, F2 = F + tf;
        double jhi = (double)i2 / (double)(G + i2 - F2);
        acc = ((bin + 0.5) * (double)(RANGE / NBINS)) * (jhi - jprev);
    }

    #pragma unroll
    for (int off = 32; off > 0; off >>= 1) acc += __shfl_down(acc, off, 64);
    __shared__ double sd[8];
    if (lane == 0) sd[wv] = acc;
    __syncthreads();
    if (t == 0) {
        double s = 0.0;
        #pragma unroll
        for (int k = 0; k < 8; ++k) s += sd[k];
        atomicAdd(out, (float)(s / NCLS));
    }
}

extern "C" void kernel_launch(void* const* d_in, const int* in_sizes, int n_in,
                              void* d_out, int out_size, void* d_ws, size_t ws_size,
                              hipStream_t stream) {
    const float* pred  = (const float*)d_in[0];
    const int*   label = (const int*)d_in[1];
    float* out = (float*)d_out;

    char* ws = (char*)d_ws;
    unsigned char* lbl = (unsigned char*)ws;                     // 1 MB
    size_t off = (size_t)NPIX;
    unsigned long long* hist = (unsigned long long*)(ws + off);  // 40.3 KB
    off += (size_t)NCLS * NBINS * 8;
    unsigned int* cnt = (unsigned int*)(ws + off);               // 84 B

    k_argmax<<<NPIX / 4 / 256, 256, 0, stream>>>((const iv4*)label, (uchar4*)lbl,
                                                 hist, cnt, out);
    dim3 hgrid(NCHUNK, NCLS);
    k_hist<<<hgrid, 512, 0, stream>>>((const fv4*)pred, (const uint2*)lbl,
                                      hist, cnt, out);
}

// Round 17
// 37.361 us; speedup vs baseline: 4.1429x; 4.1429x over previous
//
#include <hip/hip_runtime.h>

constexpr int NPIX  = 1 << 20;      // 1024*1024 pixels
constexpr int NCLS  = 21;
constexpr int NBINS = 240;          // linear bins over [0,8): width = 1/30
constexpr float RANGE = 8.0f;
constexpr float BIN_SCALE = NBINS / RANGE;   // 30
constexpr int NCHUNK = 32;
constexpr int CHUNK_PIX = NPIX / NCHUNK;     // 32768 (fits u16 bin counts)

typedef int   iv4 __attribute__((ext_vector_type(4)));
typedef float fv4 __attribute__((ext_vector_type(4)));

// ---------------------------------------------------------------------------
// 1) per-pixel argmax (single-phase label stream, ~6 TB/s = copy ceiling).
//    int4 loads, uchar4 result (1 MB -> L2-resident for k_hist's re-reads).
//    Block 0 also zeroes the global hist (40.3 KB) and out[0].
// ---------------------------------------------------------------------------
__global__ void k_argmax(const iv4* __restrict__ label4, uchar4* __restrict__ lbl,
                         unsigned long long* __restrict__ hist,
                         float* __restrict__ out) {
    int i = blockIdx.x * blockDim.x + threadIdx.x;     // over NPIX/4
    if (blockIdx.x == 0) {
        for (int b = threadIdx.x; b < NCLS * NBINS; b += blockDim.x)
            hist[b] = 0ULL;
        if (threadIdx.x == 0) out[0] = 0.0f;
    }
    if (i >= NPIX / 4) return;
    iv4 best = label4[i];
    int bx = 0, by = 0, bz = 0, bw = 0;
    #pragma unroll
    for (int c = 1; c < NCLS; ++c) {
        iv4 v = label4[(size_t)c * (NPIX / 4) + i];
        if (v.x > best.x) { best.x = v.x; bx = c; }    // strict > keeps FIRST max
        if (v.y > best.y) { best.y = v.y; by = c; }
        if (v.z > best.z) { best.z = v.z; bz = c; }
        if (v.w > best.w) { best.w = v.w; bw = c; }
    }
    lbl[i] = make_uchar4((unsigned char)bx, (unsigned char)by,
                         (unsigned char)bz, (unsigned char)bw);
}

// ---------------------------------------------------------------------------
// 2) per-(chunk, class) histogram with 4-way replicated LDS sub-histograms
//    (copy = lane&3, cuts same-bin atomic serialization 4x). 8 pixels per
//    thread-iteration; FULL unroll of the pair loop (8 iters -> max MLP).
//    Flush: packed sum of 4 copies, one u64 global atomic per bin.
// ---------------------------------------------------------------------------
__global__ void __launch_bounds__(512)
k_hist(const fv4* __restrict__ pred4, const uint2* __restrict__ lbl8,
       unsigned long long* __restrict__ hist) {
    __shared__ unsigned int sh[4][NBINS];              // 3.75 KB
    const int chunk = blockIdx.x;
    const int c     = blockIdx.y;
    const int t     = threadIdx.x;
    const int cp    = t & 3;

    for (int b = t; b < 4 * NBINS; b += 512) sh[b / NBINS][b % NBINS] = 0u;
    __syncthreads();

    const size_t pbase4 = ((size_t)c * NPIX + (size_t)chunk * CHUNK_PIX) / 4;
    const size_t lbase8 = ((size_t)chunk * CHUNK_PIX) / 8;
    constexpr int NPAIR = CHUNK_PIX / 8;               // 4096 quad-pairs

    #pragma unroll
    for (int k = t; k < NPAIR; k += 512) {             // exactly 8 iterations
        fv4 p0 = pred4[pbase4 + 2 * k];
        fv4 p1 = pred4[pbase4 + 2 * k + 1];
        uint2 lw = lbl8[lbase8 + k];                   // 8 packed uchar labels
        unsigned int la = lw.x, lb = lw.y;

        float pe[8] = { p0.x, p0.y, p0.z, p0.w, p1.x, p1.y, p1.z, p1.w };
        unsigned int lc[8] = { la & 0xFFu, (la >> 8) & 0xFFu,
                               (la >> 16) & 0xFFu, la >> 24,
                               lb & 0xFFu, (lb >> 8) & 0xFFu,
                               (lb >> 16) & 0xFFu, lb >> 24 };
        #pragma unroll
        for (int j = 0; j < 8; ++j) {
            unsigned int fg = (lc[j] == (unsigned int)c) ? 1u : 0u;
            float e = fabsf((float)fg - pe[j]);
            int bin = (int)(e * BIN_SCALE);
            bin = bin < NBINS - 1 ? bin : NBINS - 1;
            atomicAdd(&sh[cp][bin], 1u | (fg << 16));
        }
    }
    __syncthreads();

    // flush: packed sum of the 4 copies, one u64 atomic per non-empty bin
    for (int b = t; b < NBINS; b += 512) {
        unsigned int v = sh[0][b] + sh[1][b] + sh[2][b] + sh[3][b];
        if (v) {
            unsigned long long add =
                (unsigned long long)(v & 0xFFFFu) |
                ((unsigned long long)(v >> 16) << 32);
            atomicAdd(&hist[(size_t)c * NBINS + b], add);
        }
    }
}

// ---------------------------------------------------------------------------
// 3) per-class descending scan + Lovasz dot + mean: one block per class
//    (256 threads, 4 waves); thread t owns descending rank t (bin NBINS-1-t);
//    shuffle-scan, then one atomicAdd of loss_c/NCLS into out[0].
// ---------------------------------------------------------------------------
__global__ void __launch_bounds__(256)
k_scanfinal(const unsigned long long* __restrict__ hist, float* __restrict__ out) {
    const int c    = blockIdx.x;
    const int t    = threadIdx.x;
    const int lane = t & 63;
    const int wv   = t >> 6;                           // 4 waves

    const int bin = NBINS - 1 - t;                     // valid when t < NBINS
    unsigned int tn = 0, tf = 0;
    if (t < NBINS) {
        unsigned long long v = hist[(size_t)c * NBINS + bin];
        tn = (unsigned int)v;
        tf = (unsigned int)(v >> 32);
    }

    // wave-inclusive scan of (tn, tf)
    unsigned int in_ = tn, if_ = tf;
    #pragma unroll
    for (int off = 1; off < 64; off <<= 1) {
        unsigned int an = __shfl_up(in_, off, 64);
        unsigned int af = __shfl_up(if_, off, 64);
        if (lane >= off) { in_ += an; if_ += af; }
    }

    __shared__ unsigned int swn[4], swf[4];
    if (lane == 63) { swn[wv] = in_; swf[wv] = if_; }
    __syncthreads();

    if (wv == 0 && lane < 4) {                         // scan the 4 wave totals
        unsigned int a = swn[lane], b = swf[lane];
        #pragma unroll
        for (int off = 1; off < 4; off <<= 1) {
            unsigned int an = __shfl_up(a, off, 64);
            unsigned int af = __shfl_up(b, off, 64);
            if (lane >= off) { a += an; b += af; }
        }
        swn[lane] = a; swf[lane] = b;                  // inclusive wave prefixes
    }
    __syncthreads();

    const unsigned int G = swf[3];                     // total foreground count
    unsigned int i = in_ - tn + (wv ? swn[wv - 1] : 0u);   // exclusive prefix
    unsigned int F = if_ - tf + (wv ? swf[wv - 1] : 0u);

    double acc = 0.0;
    if (tn) {
        double jprev = (i > 0) ? (double)i / (double)(G + i - F) : 0.0;
        unsigned int i2 = i + tn, F2 = F + tf;
        double jhi = (double)i2 / (double)(G + i2 - F2);
        acc = ((bin + 0.5) * (double)(RANGE / NBINS)) * (jhi - jprev);
    }

    // block reduce, then one atomicAdd per class
    #pragma unroll
    for (int off = 32; off > 0; off >>= 1) acc += __shfl_down(acc, off, 64);
    __shared__ double sd[4];
    if (lane == 0) sd[wv] = acc;
    __syncthreads();
    if (t == 0) {
        double s = sd[0] + sd[1] + sd[2] + sd[3];
        atomicAdd(out, (float)(s / NCLS));
    }
}

extern "C" void kernel_launch(void* const* d_in, const int* in_sizes, int n_in,
                              void* d_out, int out_size, void* d_ws, size_t ws_size,
                              hipStream_t stream) {
    const float* pred  = (const float*)d_in[0];
    const int*   label = (const int*)d_in[1];
    float* out = (float*)d_out;

    char* ws = (char*)d_ws;
    unsigned char* lbl = (unsigned char*)ws;                     // 1 MB
    size_t off = (size_t)NPIX;
    unsigned long long* hist = (unsigned long long*)(ws + off);  // 40.3 KB

    k_argmax<<<NPIX / 4 / 256, 256, 0, stream>>>((const iv4*)label, (uchar4*)lbl,
                                                 hist, out);
    dim3 hgrid(NCHUNK, NCLS);
    k_hist<<<hgrid, 512, 0, stream>>>((const fv4*)pred, (const uint2*)lbl, hist);
    k_scanfinal<<<NCLS, 256, 0, stream>>>(hist, out);
}